// Round 10
// baseline (876.171 us; speedup 1.0000x reference)
//
#include <hip/hip_runtime.h>
#include <hip/hip_bf16.h>

#define TDIM 1024
#define NEXP 8
#define NHID 4096

typedef __hip_bfloat16 bf16;
typedef __attribute__((ext_vector_type(8))) short bf16x8;
typedef __attribute__((ext_vector_type(8))) unsigned short u16x8;
typedef __attribute__((ext_vector_type(4))) float f32x4;

__device__ __forceinline__ void gload_lds16(void* lds, const void* g) {
  __builtin_amdgcn_global_load_lds(
      (const __attribute__((address_space(1))) unsigned int*)g,
      (__attribute__((address_space(3))) unsigned int*)lds, 16, 0, 0);
}

__device__ __forceinline__ unsigned short f2bf_bits(float f) {
  __hip_bfloat16 b = __float2bfloat16(f);
  unsigned short u;
  __builtin_memcpy(&u, &b, 2);
  return u;
}

__device__ __forceinline__ float bf2f(unsigned short u) {
  union { unsigned int i; float f; } c;
  c.i = ((unsigned int)u) << 16;
  return c.f;
}

// k-octet-blocked weight convert: in [E][K][N] f32 -> chunk c = (e*(K/8)+kq)*N + n holds
// 8 bf16 {W[kq*8+j][n]}. Fully coalesced reads and writes; no LDS, no barrier.
__device__ __forceinline__ void cvt_chunk(const float* __restrict__ src, bf16* __restrict__ dst,
                                          int c, int kqShift, int nMask, int rowLen) {
  const int kq = c >> kqShift;  // includes e
  const int n = c & nMask;
  const float* s = src + ((size_t)kq * 8) * rowLen + n;
  u16x8 o;
#pragma unroll
  for (int j = 0; j < 8; ++j) o[j] = f2bf_bits(s[(size_t)j * rowLen]);
  *reinterpret_cast<u16x8*>(dst + (size_t)c * 8) = o;
}

// ---------------- prep: W1 convert + router(+x->bf16) ----------------
__global__ __launch_bounds__(256) void prep_kernel(
    const float* __restrict__ W1, bf16* __restrict__ W1C, const float* __restrict__ x,
    bf16* __restrict__ xb, const float* __restrict__ Wr, int* __restrict__ idx,
    float* __restrict__ wtok, int* __restrict__ cnt, int T) {
  __shared__ float xs[4][1024];
  const int pb = blockIdx.x;
  const int tid = threadIdx.x;
  if (pb < 4096) {
    const int id = pb * 256 + tid;  // [0, 1M)
#pragma unroll
    for (int v = 0; v < 4; ++v) cvt_chunk(W1, W1C, id + v * (1 << 20), 12, 4095, 4096);
  } else {
    const int p = pb - 4096;
    const int wave = p * 4 + (tid >> 6);
    const int lane = tid & 63;
    if (wave >= T) return;
    float* xrow = xs[tid >> 6];
    const float4* xr4 = reinterpret_cast<const float4*>(x + (size_t)wave * TDIM);
    bf16* xbrow = xb + (size_t)wave * TDIM;
#pragma unroll
    for (int i = 0; i < TDIM / 256; ++i) {
      float4 xv = xr4[lane + i * 64];
      ushort4 o;
      o.x = f2bf_bits(xv.x);
      o.y = f2bf_bits(xv.y);
      o.z = f2bf_bits(xv.z);
      o.w = f2bf_bits(xv.w);
      *reinterpret_cast<ushort4*>(xbrow + (lane + i * 64) * 4) = o;
      *reinterpret_cast<float4*>(&xrow[(lane + i * 64) * 4]) = xv;
    }
    float acc[NEXP];
#pragma unroll
    for (int e = 0; e < NEXP; ++e) acc[e] = 0.f;
    const float4* wr4 = reinterpret_cast<const float4*>(Wr);
#pragma unroll
    for (int i = 0; i < TDIM / 64; ++i) {
      float xv = xrow[lane + i * 64];
      float4 wa = wr4[(lane + i * 64) * 2];
      float4 wb = wr4[(lane + i * 64) * 2 + 1];
      acc[0] += xv * wa.x;
      acc[1] += xv * wa.y;
      acc[2] += xv * wa.z;
      acc[3] += xv * wa.w;
      acc[4] += xv * wb.x;
      acc[5] += xv * wb.y;
      acc[6] += xv * wb.z;
      acc[7] += xv * wb.w;
    }
#pragma unroll
    for (int e = 0; e < NEXP; ++e) {
      float v = acc[e];
#pragma unroll
      for (int s = 32; s; s >>= 1) v += __shfl_xor(v, s);
      acc[e] = v;
    }
    if (lane == 0) {
      int e0 = 0;
      float l0 = acc[0];
      for (int e = 1; e < NEXP; ++e)
        if (acc[e] > l0) { l0 = acc[e]; e0 = e; }
      int e1 = -1;
      float l1 = -INFINITY;
      for (int e = 0; e < NEXP; ++e)
        if (e != e0 && acc[e] > l1) { l1 = acc[e]; e1 = e; }
      float z = __expf(l1 - l0);
      idx[wave * 2] = e0;
      idx[wave * 2 + 1] = e1;
      wtok[wave * 2] = 1.f / (1.f + z);
      wtok[wave * 2 + 1] = z / (1.f + z);
      atomicAdd(&cnt[e0], 1);
      atomicAdd(&cnt[e1], 1);
    }
  }
}

__global__ void scan_kernel(const int* __restrict__ cnt, int* __restrict__ offs) {
  if (threadIdx.x == 0 && blockIdx.x == 0) {
    int s = 0;
    for (int e = 0; e < NEXP; ++e) { offs[e] = s; s += cnt[e]; }
  }
}

__global__ void build_perm_kernel(const int* __restrict__ idx, const int* __restrict__ offs,
                                  int* __restrict__ fill, int* __restrict__ perm,
                                  int* __restrict__ islot, int T) {
  int t = blockIdx.x * blockDim.x + threadIdx.x;
  if (t >= T) return;
#pragma unroll
  for (int k = 0; k < 2; ++k) {
    int e = idx[t * 2 + k];
    int p = offs[e] + atomicAdd(&fill[e], 1);
    perm[p] = t;
    islot[t * 2 + k] = p;
  }
}

// ---------------- grouped GEMM, m97 recipe: 128x128, BK=32, 4 waves, ~3 blocks/CU ----------
// A LDS: row-major [128 row][32 k] per buf (slot t: row=t>>2, kslot=t&3; src 64B contig/row).
// B LDS: k-octet-major [4 jo][128 row] chunks per buf (slot t: jo=t>>7, row=t&127;
//   src = (oct*ND + n)*8 -> each wave stages 1KB CONTIGUOUS global).
// Loop: stage(next buf) -> read frags(cur) -> 16 MFMA -> __syncthreads (compiler-drained).
// Cross-block overlap at ~3 blocks/CU hides the drain (m97/m114 regime).
// MBMAJOR picks block order within expert for L2: GEMM1 nb-major (A panel L2-resident),
// GEMM2 mb-major (B slice streams, A slice resident).
template <int KD, int ND, bool GATHER, bool GELU, bool CONV, bool MBMAJOR>
__global__ __launch_bounds__(256) void moe_gemm97(
    const bf16* __restrict__ A, const bf16* __restrict__ BC, const float* __restrict__ bias,
    const int* __restrict__ perm, const int* __restrict__ cnt, const int* __restrict__ offs,
    bf16* __restrict__ Dst, int nm, int nn, const float* __restrict__ Wsrc,
    bf16* __restrict__ Wdst) {
  __shared__ short sA[2][4096];  // 8 KiB per buf
  __shared__ short sB[2][4096];  // 8 KiB per buf

  const int nwg = NEXP * nm * nn;
  const int bid = blockIdx.x;
  if (CONV && bid >= nwg) {
    const int id = (bid - nwg) * 256 + threadIdx.x;  // [0, 512K)
#pragma unroll
    for (int v = 0; v < 8; ++v) cvt_chunk(Wsrc, Wdst, id + v * (1 << 19), 10, 1023, 1024);
    return;
  }
  const int wg = (bid & 7) * (nwg >> 3) + (bid >> 3);  // bijective: nwg % 8 == 0
  const int e = wg / (nm * nn);
  const int rem = wg % (nm * nn);
  const int mb = MBMAJOR ? rem / nn : rem % nm;
  const int nb = MBMAJOR ? rem % nn : rem / nm;

  const int ce = cnt[e];
  const int m0 = mb * 128;
  if (m0 >= ce) return;
  const int base = offs[e];
  const int n0 = nb * 128;
  const int tid = threadIdx.x;
  const int lane = tid & 63;
  const int wid = tid >> 6;
  const int wm = wid >> 1, wn = wid & 1;
  const int lcol = lane & 15;
  const int lk = lane >> 4;  // 0..3

  // staging pointers (slots t = tid, tid+256)
  const bf16* aP[2];
  const bf16* bP[2];
#pragma unroll
  for (int i = 0; i < 2; ++i) {
    int t = tid + i * 256;
    int srow = t >> 2, ks = t & 3;
    int grow = m0 + srow;
    if (grow > ce - 1) grow = ce - 1;
    size_t arow = GATHER ? (size_t)perm[base + grow] : (size_t)(base + grow);
    aP[i] = A + arow * KD + ks * 8;
    int jo = t >> 7, brow = t & 127;
    bP[i] = BC + (size_t)e * KD * ND + ((size_t)jo * ND + (n0 + brow)) * 8;
  }

  f32x4 acc[4][4];
#pragma unroll
  for (int m = 0; m < 4; ++m)
#pragma unroll
    for (int n = 0; n < 4; ++n) acc[m][n] = (f32x4){0.f, 0.f, 0.f, 0.f};

#define STAGE(BUF, k0)                                                    \
  {                                                                       \
    gload_lds16((char*)sA[BUF] + tid * 16, aP[0] + (k0));                 \
    gload_lds16((char*)sA[BUF] + 4096 + tid * 16, aP[1] + (k0));          \
    gload_lds16((char*)sB[BUF] + tid * 16, bP[0] + (size_t)(k0)*ND);      \
    gload_lds16((char*)sB[BUF] + 4096 + tid * 16, bP[1] + (size_t)(k0)*ND); \
  }

  STAGE(0, 0);
  __syncthreads();

  const int NT = KD / 32;
  for (int kt = 0; kt < NT; ++kt) {
    const int cur = kt & 1;
    if (kt + 1 < NT) STAGE(cur ^ 1, (kt + 1) * 32);
    const short* Ab = sA[cur];
    const short* Bb = sB[cur];
    bf16x8 fA[4], fB[4];
#pragma unroll
    for (int n = 0; n < 4; ++n)
      fB[n] = *(const bf16x8*)(Bb + ((size_t)lk * 128 + wn * 64 + n * 16 + lcol) * 8);
#pragma unroll
    for (int m = 0; m < 4; ++m)
      fA[m] = *(const bf16x8*)(Ab + ((size_t)(wm * 64 + m * 16 + lcol)) * 32 + lk * 8);
#pragma unroll
    for (int m = 0; m < 4; ++m)
#pragma unroll
      for (int n = 0; n < 4; ++n)
        acc[m][n] = __builtin_amdgcn_mfma_f32_16x16x32_bf16(fA[m], fB[n], acc[m][n], 0, 0, 0);
    __syncthreads();
  }
#undef STAGE

  // epilogue (R1-verified mapping): row = m0+wm*64+m*16+(lane>>4)*4+r; col = n0+wn*64+n*16+lcol
  float bv[4];
#pragma unroll
  for (int n = 0; n < 4; ++n) bv[n] = bias[e * ND + n0 + wn * 64 + n * 16 + lcol];
  const int lr4 = lk * 4;
#pragma unroll
  for (int m = 0; m < 4; ++m)
#pragma unroll
    for (int r = 0; r < 4; ++r) {
      int grow = m0 + wm * 64 + m * 16 + lr4 + r;
      if (grow < ce) {
        bf16* drow = Dst + (size_t)(base + grow) * ND;
#pragma unroll
        for (int n = 0; n < 4; ++n) {
          int col = n0 + wn * 64 + n * 16 + lcol;
          float v = acc[m][n][r] + bv[n];
          if (GELU) v = 0.5f * v * (1.0f + erff(v * 0.70710678118654752f));
          drow[col] = __float2bfloat16(v);
        }
      }
    }
}

// ---------------- combine: out[t] = w0*y[slot0] + w1*y[slot1] ----------------
__global__ void combine_kernel(const bf16* __restrict__ y, const int* __restrict__ islot,
                               const float* __restrict__ wtok, float* __restrict__ out) {
  const int t = blockIdx.x;
  const int d = threadIdx.x * 4;
  const int s0 = islot[t * 2], s1 = islot[t * 2 + 1];
  const float w0 = wtok[t * 2], w1 = wtok[t * 2 + 1];
  ushort4 ya = *reinterpret_cast<const ushort4*>(y + (size_t)s0 * TDIM + d);
  ushort4 yb = *reinterpret_cast<const ushort4*>(y + (size_t)s1 * TDIM + d);
  float4 o;
  o.x = w0 * bf2f(ya.x) + w1 * bf2f(yb.x);
  o.y = w0 * bf2f(ya.y) + w1 * bf2f(yb.y);
  o.z = w0 * bf2f(ya.z) + w1 * bf2f(yb.z);
  o.w = w0 * bf2f(ya.w) + w1 * bf2f(yb.w);
  *reinterpret_cast<float4*>(out + (size_t)t * TDIM + d) = o;
}

extern "C" void kernel_launch(void* const* d_in, const int* in_sizes, int n_in, void* d_out,
                              int out_size, void* d_ws, size_t ws_size, hipStream_t stream) {
  const float* x = (const float*)d_in[0];
  const float* Wr = (const float*)d_in[1];
  const float* W1 = (const float*)d_in[2];
  const float* b1 = (const float*)d_in[3];
  const float* W2 = (const float*)d_in[4];
  const float* b2 = (const float*)d_in[5];
  float* out = (float*)d_out;
  const int T = in_sizes[0] / TDIM;  // 8192

  size_t off = 0;
  auto alloc = [&](size_t bytes) {
    void* q = (char*)d_ws + off;
    off += (bytes + 255) & ~(size_t)255;
    return q;
  };
  bf16* xb = (bf16*)alloc((size_t)T * TDIM * 2);
  bf16* W1C = (bf16*)alloc((size_t)NEXP * TDIM * NHID * 2);
  bf16* W2C = (bf16*)alloc((size_t)NEXP * TDIM * NHID * 2);
  bf16* h = (bf16*)alloc((size_t)2 * T * NHID * 2);
  int* idx = (int*)alloc((size_t)T * 2 * 4);
  float* wtok = (float*)alloc((size_t)T * 2 * 4);
  int* perm = (int*)alloc((size_t)T * 2 * 4);
  int* islot = (int*)alloc((size_t)T * 2 * 4);
  int* cnt = (int*)alloc(256);  // cnt[8] | fill[8] | offs[8]
  int* fill = cnt + 8;
  int* offs = cnt + 16;
  // y (32 MB bf16) aliases W1C (64 MB): W1C dead after GEMM1; y written by GEMM2, read by combine.
  bf16* y = W1C;

  hipMemsetAsync(cnt, 0, 64, stream);  // cnt + fill

  prep_kernel<<<6144, 256, 0, stream>>>(W1, W1C, x, xb, Wr, idx, wtok, cnt, T);
  scan_kernel<<<1, 64, 0, stream>>>(cnt, offs);
  build_perm_kernel<<<(T + 255) / 256, 256, 0, stream>>>(idx, offs, fill, perm, islot, T);

  // GEMM1: nm=32 (4096 rows/expert worst; actual ~2048), nn=32; nb-major; +2048 conv blocks.
  moe_gemm97<TDIM, NHID, true, true, true, false><<<NEXP * 32 * 32 + 2048, 256, 0, stream>>>(
      xb, W1C, b1, perm, cnt, offs, h, 32, 32, W2, W2C);
  // GEMM2: nm=32, nn=8; mb-major.
  moe_gemm97<NHID, TDIM, false, false, false, true><<<NEXP * 32 * 8, 256, 0, stream>>>(
      h, W2C, b2, perm, cnt, offs, y, 32, 8, nullptr, nullptr);

  combine_kernel<<<T, 256, 0, stream>>>(y, islot, wtok, out);
}

// Round 13
// 783.791 us; speedup vs baseline: 1.1179x; 1.1179x over previous
//
#include <hip/hip_runtime.h>
#include <hip/hip_bf16.h>

#define TDIM 1024
#define NEXP 8
#define NHID 4096

typedef __hip_bfloat16 bf16;
typedef __attribute__((ext_vector_type(8))) short bf16x8;
typedef __attribute__((ext_vector_type(8))) unsigned short u16x8;
typedef __attribute__((ext_vector_type(4))) float f32x4;

__device__ __forceinline__ void gload_lds16(void* lds, const void* g) {
  __builtin_amdgcn_global_load_lds(
      (const __attribute__((address_space(1))) unsigned int*)g,
      (__attribute__((address_space(3))) unsigned int*)lds, 16, 0, 0);
}

__device__ __forceinline__ unsigned short f2bf_bits(float f) {
  __hip_bfloat16 b = __float2bfloat16(f);
  unsigned short u;
  __builtin_memcpy(&u, &b, 2);
  return u;
}

__device__ __forceinline__ float bf2f(unsigned short u) {
  union { unsigned int i; float f; } c;
  c.i = ((unsigned int)u) << 16;
  return c.f;
}

// float4-quad k-octet convert: thread handles 4 consecutive chunks (same k-octet kqg,
// cols 4*ng..+3). Reads 8 float4 (fully coalesced), writes 64B contiguous.
// gid = kqg * (N/4) + ng ; kqg includes e.  Total gids = E*(K/8)*(N/4).
__device__ __forceinline__ void cvt_quad(const float* __restrict__ src, bf16* __restrict__ dst,
                                         int gid, int ngShift, int rowLen) {
  const int kqg = gid >> ngShift;
  const int ng = gid & ((1 << ngShift) - 1);
  const float* s = src + ((size_t)kqg * 8) * rowLen + ng * 4;
  float4 v[8];
#pragma unroll
  for (int j = 0; j < 8; ++j) v[j] = *reinterpret_cast<const float4*>(s + (size_t)j * rowLen);
  u16x8 o[4];
#pragma unroll
  for (int c = 0; c < 4; ++c)
#pragma unroll
    for (int j = 0; j < 8; ++j) o[c][j] = f2bf_bits((&v[j].x)[c]);
  bf16* d = dst + ((size_t)kqg * rowLen + ng * 4) * 8;  // 4 chunks = 64B contiguous
#pragma unroll
  for (int c = 0; c < 4; ++c) *reinterpret_cast<u16x8*>(d + c * 8) = o[c];
}

// ---------------- prep: W1 convert (float4-quad) + router(+x->bf16) ----------------
// W1: 8*(1024/8)*(4096/4) = 1M gids -> blocks [0,4096) x 256.
// blocks [4096,6144): router + x->bf16 (4 token-waves/block).
__global__ __launch_bounds__(256) void prep_kernel(
    const float* __restrict__ W1, bf16* __restrict__ W1C, const float* __restrict__ x,
    bf16* __restrict__ xb, const float* __restrict__ Wr, int* __restrict__ idx,
    float* __restrict__ wtok, int* __restrict__ cnt, int T) {
  __shared__ float xs[4][1024];
  const int pb = blockIdx.x;
  const int tid = threadIdx.x;
  if (pb < 4096) {
    cvt_quad(W1, W1C, pb * 256 + tid, 10, 4096);
  } else {
    const int p = pb - 4096;
    const int wave = p * 4 + (tid >> 6);
    const int lane = tid & 63;
    if (wave >= T) return;
    float* xrow = xs[tid >> 6];
    const float4* xr4 = reinterpret_cast<const float4*>(x + (size_t)wave * TDIM);
    bf16* xbrow = xb + (size_t)wave * TDIM;
#pragma unroll
    for (int i = 0; i < TDIM / 256; ++i) {
      float4 xv = xr4[lane + i * 64];
      ushort4 o;
      o.x = f2bf_bits(xv.x);
      o.y = f2bf_bits(xv.y);
      o.z = f2bf_bits(xv.z);
      o.w = f2bf_bits(xv.w);
      *reinterpret_cast<ushort4*>(xbrow + (lane + i * 64) * 4) = o;
      *reinterpret_cast<float4*>(&xrow[(lane + i * 64) * 4]) = xv;
    }
    float acc[NEXP];
#pragma unroll
    for (int e = 0; e < NEXP; ++e) acc[e] = 0.f;
    const float4* wr4 = reinterpret_cast<const float4*>(Wr);
#pragma unroll
    for (int i = 0; i < TDIM / 64; ++i) {
      float xv = xrow[lane + i * 64];
      float4 wa = wr4[(lane + i * 64) * 2];
      float4 wb = wr4[(lane + i * 64) * 2 + 1];
      acc[0] += xv * wa.x;
      acc[1] += xv * wa.y;
      acc[2] += xv * wa.z;
      acc[3] += xv * wa.w;
      acc[4] += xv * wb.x;
      acc[5] += xv * wb.y;
      acc[6] += xv * wb.z;
      acc[7] += xv * wb.w;
    }
#pragma unroll
    for (int e = 0; e < NEXP; ++e) {
      float v = acc[e];
#pragma unroll
      for (int s = 32; s; s >>= 1) v += __shfl_xor(v, s);
      acc[e] = v;
    }
    if (lane == 0) {
      int e0 = 0;
      float l0 = acc[0];
      for (int e = 1; e < NEXP; ++e)
        if (acc[e] > l0) { l0 = acc[e]; e0 = e; }
      int e1 = -1;
      float l1 = -INFINITY;
      for (int e = 0; e < NEXP; ++e)
        if (e != e0 && acc[e] > l1) { l1 = acc[e]; e1 = e; }
      float z = __expf(l1 - l0);
      idx[wave * 2] = e0;
      idx[wave * 2 + 1] = e1;
      wtok[wave * 2] = 1.f / (1.f + z);
      wtok[wave * 2 + 1] = z / (1.f + z);
      atomicAdd(&cnt[e0], 1);
      atomicAdd(&cnt[e1], 1);
    }
  }
}

__global__ void scan_kernel(const int* __restrict__ cnt, int* __restrict__ offs) {
  if (threadIdx.x == 0 && blockIdx.x == 0) {
    int s = 0;
    for (int e = 0; e < NEXP; ++e) { offs[e] = s; s += cnt[e]; }
  }
}

__global__ void build_perm_kernel(const int* __restrict__ idx, const int* __restrict__ offs,
                                  int* __restrict__ fill, int* __restrict__ perm,
                                  int* __restrict__ islot, int T) {
  int t = blockIdx.x * blockDim.x + threadIdx.x;
  if (t >= T) return;
#pragma unroll
  for (int k = 0; k < 2; ++k) {
    int e = idx[t * 2 + k];
    int p = offs[e] + atomicAdd(&fill[e], 1);
    perm[p] = t;
    islot[t * 2 + k] = p;
  }
}

// asm ds_read_b128: compiler-invisible LDS read (no auto vmcnt(0) vs global_load_lds).
#define DSR(dst, va, IMM) \
  asm volatile("ds_read_b128 %0, %1 offset:%2" : "=&v"(dst) : "v"(va), "i"(IMM))

// ---------------- grouped GEMM: 256x256x64, 8-phase (R9-verified structure) ----------------
// A LDS: row-major [row][kslot] per half, XOR-swizzled; B LDS: k-octet-major [jo][row].
// Phase: [asm ds_reads from CBUF] [stage 1 half-tile] [vmcnt(4) at listed] [barrier]
//        [lgkmcnt(0); sched_barrier] [setprio1 16 MFMA setprio0] [barrier]
// Single fragment set (VGPR ~120, no spills — R11/R12's double-set read-ahead spilled
// asm ds_read outputs -> corruption).
template <int KD, int ND, bool GATHER, bool GELU, bool CONV>
__global__ __launch_bounds__(512, 2) void moe_gemm8(
    const bf16* __restrict__ A, const bf16* __restrict__ BC, const float* __restrict__ bias,
    const int* __restrict__ perm, const int* __restrict__ cnt, const int* __restrict__ offs,
    bf16* __restrict__ Dst, int nm, int nn, const float* __restrict__ Wsrc,
    bf16* __restrict__ Wdst) {
  __shared__ short lds[65536];  // 128 KiB

  const int nwg = NEXP * nm * nn;
  const int bid = blockIdx.x;
  if (CONV && bid >= nwg) {
    const int gid = (bid - nwg) * 512 + threadIdx.x;  // [0, 1M) quads = 4M chunks
    cvt_quad(Wsrc, Wdst, gid, 8, 1024);
    return;
  }
  const int wg = (bid & 7) * (nwg >> 3) + (bid >> 3);  // bijective: nwg % 8 == 0
  const int e = wg / (nm * nn);
  const int rem = wg % (nm * nn);
  const int mb = rem / nn, nb = rem % nn;

  const int ce = cnt[e];
  const int m0 = mb * 256;
  if (m0 >= ce) return;
  const int base = offs[e];
  const int n0 = nb * 256;
  const int tid = threadIdx.x;
  const int lane = tid & 63;
  const int wid = tid >> 6;
  const int wm = wid >> 2, wn = wid & 3;
  const int lcol = lane & 15;

  // A read addresses (swizzled row-major image).
  const unsigned ldsb = (unsigned)(size_t)&lds[0];
  const int v4 = lane >> 4;
  const int j7 = lcol & 7;
  const unsigned bk0 = (unsigned)((v4 ^ j7) << 4);
  const unsigned bk1 = (unsigned)(((v4 + 4) ^ j7) << 4);
  const unsigned aBase = ldsb + (unsigned)((wm * 64 + lcol) * 128);
  const unsigned vaA00 = aBase + bk0, vaA01 = aBase + bk1;
  const unsigned vaA10 = aBase + 65536u + bk0, vaA11 = aBase + 65536u + bk1;
  // B read addresses (k-octet-major image).
  const unsigned bBase = ldsb + 32768u + (unsigned)(v4 * 2048 + (wn * 32 + lcol) * 16);
  const unsigned vaB0 = bBase, vaB1 = bBase + 65536u;

  // staging pointers (A: row-major swizzled src; B: k-octet rows contiguous).
  const bf16* aP[2][2];
  const bf16* bP[2][2];
#pragma unroll
  for (int h = 0; h < 2; ++h)
#pragma unroll
    for (int i = 0; i < 2; ++i) {
      int s = tid + i * 512;
      int srow = s >> 3;
      int ksrc = (s & 7) ^ (srow & 7);
      int grow = m0 + h * 128 + srow;
      if (grow > ce - 1) grow = ce - 1;
      size_t arow = GATHER ? (size_t)perm[base + grow] : (size_t)(base + grow);
      aP[h][i] = A + arow * KD + ksrc * 8;
      int jo = s >> 7, brow = s & 127;
      bP[h][i] = BC + (size_t)e * KD * ND + ((size_t)jo * ND + (n0 + h * 128 + brow)) * 8;
    }

  f32x4 acc[8][4];
#pragma unroll
  for (int m = 0; m < 8; ++m)
#pragma unroll
    for (int n = 0; n < 4; ++n) acc[m][n] = (f32x4){0.f, 0.f, 0.f, 0.f};

  bf16x8 fA[4][2], fB[2][2];  // single set, persists across phases (compile-time indexed)

#define STAGE(SBUF, OP, HF, kA, kB)                                                  \
  {                                                                                  \
    char* sd = (char*)lds + (SBUF) * 65536 + (OP) * 32768 + (HF) * 16384 + tid * 16; \
    if (OP) {                                                                        \
      gload_lds16(sd, bP[HF][0] + (kB));                                             \
      gload_lds16(sd + 8192, bP[HF][1] + (kB));                                      \
    } else {                                                                         \
      gload_lds16(sd, aP[HF][0] + (kA));                                             \
      gload_lds16(sd + 8192, aP[HF][1] + (kA));                                      \
    }                                                                                \
  }

// QM,QN: quadrant; RA/RB: fresh A/B fragment reads (else reuse registers);
// SOP,SHF: staged (op,half); SBUF: stage buffer; CBUF: consume buffer (literal 0/1).
#define PHASE(QM, QN, RA, RB, SOP, SHF, SBUF, CBUF, kA, kB, DO_VM)                   \
  {                                                                                  \
    if (RA) {                                                                        \
      DSR(fA[0][0], vaA##CBUF##0, (QM)*16384 + 0);                                   \
      DSR(fA[0][1], vaA##CBUF##1, (QM)*16384 + 0);                                   \
      DSR(fA[1][0], vaA##CBUF##0, (QM)*16384 + 2048);                                \
      DSR(fA[1][1], vaA##CBUF##1, (QM)*16384 + 2048);                                \
      DSR(fA[2][0], vaA##CBUF##0, (QM)*16384 + 4096);                                \
      DSR(fA[2][1], vaA##CBUF##1, (QM)*16384 + 4096);                                \
      DSR(fA[3][0], vaA##CBUF##0, (QM)*16384 + 6144);                                \
      DSR(fA[3][1], vaA##CBUF##1, (QM)*16384 + 6144);                                \
    }                                                                                \
    if (RB) {                                                                        \
      DSR(fB[0][0], vaB##CBUF, (QN)*16384 + 0);                                      \
      DSR(fB[0][1], vaB##CBUF, (QN)*16384 + 8192);                                   \
      DSR(fB[1][0], vaB##CBUF, (QN)*16384 + 256);                                    \
      DSR(fB[1][1], vaB##CBUF, (QN)*16384 + 8192 + 256);                             \
    }                                                                                \
    STAGE(SBUF, SOP, SHF, kA, kB);                                                   \
    if (DO_VM) asm volatile("s_waitcnt vmcnt(4)" ::: "memory");                      \
    __builtin_amdgcn_s_barrier();                                                    \
    asm volatile("s_waitcnt lgkmcnt(0)" ::: "memory");                               \
    __builtin_amdgcn_sched_barrier(0);                                               \
    __builtin_amdgcn_s_setprio(1);                                                   \
    _Pragma("unroll") for (int mm = 0; mm < 4; ++mm)                                 \
        _Pragma("unroll") for (int n2 = 0; n2 < 2; ++n2) {                           \
      acc[(QM) * 4 + mm][(QN) * 2 + n2] = __builtin_amdgcn_mfma_f32_16x16x32_bf16(   \
          fA[mm][0], fB[n2][0], acc[(QM) * 4 + mm][(QN) * 2 + n2], 0, 0, 0);         \
      acc[(QM) * 4 + mm][(QN) * 2 + n2] = __builtin_amdgcn_mfma_f32_16x16x32_bf16(   \
          fA[mm][1], fB[n2][1], acc[(QM) * 4 + mm][(QN) * 2 + n2], 0, 0, 0);         \
    }                                                                                \
    __builtin_amdgcn_s_setprio(0);                                                   \
    __builtin_amdgcn_s_barrier();                                                    \
  }

  // prologue: tile 0 -> buf0 (A0,B0,A1,B1); vmcnt(4) => A0,B0 landed; barrier.
  STAGE(0, 0, 0, 0, 0);
  STAGE(0, 1, 0, 0, 0);
  STAGE(0, 0, 1, 0, 0);
  STAGE(0, 1, 1, 0, 0);
  asm volatile("s_waitcnt vmcnt(4)" ::: "memory");
  __builtin_amdgcn_s_barrier();

  const int NI = KD / 128;
  for (int itv = 0; itv < NI; ++itv) {
    const int k1 = itv * 128 + 64;  // tile 2it+1 -> buf1 (consumed ph4-7)
    int k2 = itv * 128 + 128;       // tile 2it+2 -> buf0 (consumed next iter)
    if (k2 >= KD) k2 = 0;           // last iter: dummy restage keeps vmcnt math
    const int k1B = k1 * ND, k2B = k2 * ND;
    PHASE(0, 0, 1, 1, 0, 0, 1, 0, k1, k1B, 1)
    PHASE(1, 0, 1, 0, 1, 0, 1, 0, k1, k1B, 1)
    PHASE(1, 1, 0, 1, 0, 1, 1, 0, k1, k1B, 0)
    PHASE(0, 1, 1, 0, 1, 1, 1, 0, k1, k1B, 1)
    PHASE(0, 0, 1, 1, 0, 0, 0, 1, k2, k2B, 1)
    PHASE(1, 0, 1, 0, 1, 0, 0, 1, k2, k2B, 1)
    PHASE(1, 1, 0, 1, 0, 1, 0, 1, k2, k2B, 0)
    PHASE(0, 1, 1, 0, 1, 1, 0, 1, k2, k2B, 1)
  }
#undef PHASE
#undef STAGE

  // epilogue: row = m0 + QM*128 + wm*64 + mm*16 + (lane>>4)*4 + r ;
  //           col = n0 + QN*128 + wn*32 + n2*16 + lcol
  float bv[4];
#pragma unroll
  for (int ni = 0; ni < 4; ++ni)
    bv[ni] = bias[e * ND + n0 + (ni >> 1) * 128 + wn * 32 + (ni & 1) * 16 + lcol];
  const int lr4 = (lane >> 4) * 4;
#pragma unroll
  for (int mi = 0; mi < 8; ++mi) {
    const int rbase = m0 + (mi >> 2) * 128 + wm * 64 + (mi & 3) * 16 + lr4;
#pragma unroll
    for (int r = 0; r < 4; ++r) {
      int grow = rbase + r;
      if (grow < ce) {
        bf16* drow = Dst + (size_t)(base + grow) * ND;
#pragma unroll
        for (int ni = 0; ni < 4; ++ni) {
          int col = n0 + (ni >> 1) * 128 + wn * 32 + (ni & 1) * 16 + lcol;
          float v = acc[mi][ni][r] + bv[ni];
          if (GELU) v = 0.5f * v * (1.0f + erff(v * 0.70710678118654752f));
          drow[col] = __float2bfloat16(v);
        }
      }
    }
  }
}

// ---------------- combine: out[t] = w0*y[slot0] + w1*y[slot1] ----------------
__global__ void combine_kernel(const bf16* __restrict__ y, const int* __restrict__ islot,
                               const float* __restrict__ wtok, float* __restrict__ out) {
  const int t = blockIdx.x;
  const int d = threadIdx.x * 4;
  const int s0 = islot[t * 2], s1 = islot[t * 2 + 1];
  const float w0 = wtok[t * 2], w1 = wtok[t * 2 + 1];
  ushort4 ya = *reinterpret_cast<const ushort4*>(y + (size_t)s0 * TDIM + d);
  ushort4 yb = *reinterpret_cast<const ushort4*>(y + (size_t)s1 * TDIM + d);
  float4 o;
  o.x = w0 * bf2f(ya.x) + w1 * bf2f(yb.x);
  o.y = w0 * bf2f(ya.y) + w1 * bf2f(yb.y);
  o.z = w0 * bf2f(ya.z) + w1 * bf2f(yb.z);
  o.w = w0 * bf2f(ya.w) + w1 * bf2f(yb.w);
  *reinterpret_cast<float4*>(out + (size_t)t * TDIM + d) = o;
}

extern "C" void kernel_launch(void* const* d_in, const int* in_sizes, int n_in, void* d_out,
                              int out_size, void* d_ws, size_t ws_size, hipStream_t stream) {
  const float* x = (const float*)d_in[0];
  const float* Wr = (const float*)d_in[1];
  const float* W1 = (const float*)d_in[2];
  const float* b1 = (const float*)d_in[3];
  const float* W2 = (const float*)d_in[4];
  const float* b2 = (const float*)d_in[5];
  float* out = (float*)d_out;
  const int T = in_sizes[0] / TDIM;  // 8192

  size_t off = 0;
  auto alloc = [&](size_t bytes) {
    void* q = (char*)d_ws + off;
    off += (bytes + 255) & ~(size_t)255;
    return q;
  };
  bf16* xb = (bf16*)alloc((size_t)T * TDIM * 2);
  bf16* W1C = (bf16*)alloc((size_t)NEXP * TDIM * NHID * 2);
  bf16* W2C = (bf16*)alloc((size_t)NEXP * TDIM * NHID * 2);
  bf16* h = (bf16*)alloc((size_t)2 * T * NHID * 2);
  int* idx = (int*)alloc((size_t)T * 2 * 4);
  float* wtok = (float*)alloc((size_t)T * 2 * 4);
  int* perm = (int*)alloc((size_t)T * 2 * 4);
  int* islot = (int*)alloc((size_t)T * 2 * 4);
  int* cnt = (int*)alloc(256);  // cnt[8] | fill[8] | offs[8]
  int* fill = cnt + 8;
  int* offs = cnt + 16;
  bf16* y = W1C;  // alias: W1C dead after GEMM1

  hipMemsetAsync(cnt, 0, 64, stream);  // cnt + fill

  prep_kernel<<<6144, 256, 0, stream>>>(W1, W1C, x, xb, Wr, idx, wtok, cnt, T);
  scan_kernel<<<1, 64, 0, stream>>>(cnt, offs);
  build_perm_kernel<<<(T + 255) / 256, 256, 0, stream>>>(idx, offs, fill, perm, islot, T);

  // GEMM1 (+2048 conv blocks stream-converting W2 -> W2C; 2048*512 = 1M quad-gids = 4M chunks)
  moe_gemm8<TDIM, NHID, true, true, true><<<NEXP * 32 * 16 + 2048, 512, 0, stream>>>(
      xb, W1C, b1, perm, cnt, offs, h, 32, 16, W2, W2C);
  moe_gemm8<NHID, TDIM, false, false, false><<<NEXP * 32 * 4, 512, 0, stream>>>(
      h, W2C, b2, perm, cnt, offs, y, 32, 4, nullptr, nullptr);

  combine_kernel<<<T, 256, 0, stream>>>(y, islot, wtok, out);
}